// Round 4
// baseline (866.671 us; speedup 1.0000x reference)
//
#include <hip/hip_runtime.h>
#include <hip/hip_bf16.h>

// Problem constants (fixed shapes from reference)
#define M_DIM 4096
#define K_DIM 4096     // IN_F
#define N_DIM 11008    // OUT_F
#define NGROUPS 32     // K/128

typedef __attribute__((ext_vector_type(8))) short  short8;
typedef __attribute__((ext_vector_type(8))) unsigned short ushort8;
typedef __attribute__((ext_vector_type(4))) float  f32x4;

// RNE float->bf16 (inputs are finite; no NaN path needed)
__device__ __forceinline__ unsigned short f2bf(float f) {
    union { float f; unsigned u; } v{f};
    unsigned r = v.u + 0x7FFFu + ((v.u >> 16) & 1u);
    return (unsigned short)(r >> 16);
}

// ---------------------------------------------------------------------------
// Pass 1a: dequantize qweight [O,K] int32 codes -> bf16 W in ws.
// Each thread: 8 consecutive K elements (2x int4 loads, 1x 16B store).
// Memory-bound: 180MB read + 90MB write.
// ---------------------------------------------------------------------------
__global__ __launch_bounds__(256) void dequant_w_kernel(
        const int* __restrict__ q, const float* __restrict__ scales,
        ushort* __restrict__ wb) {
    const int c = blockIdx.x * 256 + threadIdx.x;     // chunk of 8, 5,636,096 total
    const int row = c >> 9;                            // / (K/8 = 512)
    const int k8  = c & 511;
    const float s = scales[row * NGROUPS + (k8 >> 4)]; // group = k8*8/128
    const int4* qp = (const int4*)q + (long)c * 2;
    int4 a = qp[0], b = qp[1];
    ushort8 o;
    o[0] = f2bf((a.x - 8) * s); o[1] = f2bf((a.y - 8) * s);
    o[2] = f2bf((a.z - 8) * s); o[3] = f2bf((a.w - 8) * s);
    o[4] = f2bf((b.x - 8) * s); o[5] = f2bf((b.y - 8) * s);
    o[6] = f2bf((b.z - 8) * s); o[7] = f2bf((b.w - 8) * s);
    ((ushort8*)wb)[c] = o;
}

// ---------------------------------------------------------------------------
// Pass 1b: x fp32 -> bf16
// ---------------------------------------------------------------------------
__global__ __launch_bounds__(256) void cvt_x_kernel(
        const float* __restrict__ x, ushort* __restrict__ xb) {
    const int c = blockIdx.x * 256 + threadIdx.x;     // chunk of 8, 2,097,152 total
    const float4* xp = (const float4*)x + (long)c * 2;
    float4 a = xp[0], b = xp[1];
    ushort8 o;
    o[0] = f2bf(a.x); o[1] = f2bf(a.y); o[2] = f2bf(a.z); o[3] = f2bf(a.w);
    o[4] = f2bf(b.x); o[5] = f2bf(b.y); o[6] = f2bf(b.z); o[7] = f2bf(b.w);
    ((ushort8*)xb)[c] = o;
}

// ---------------------------------------------------------------------------
// Pass 2: bf16 GEMM, C[M,N] = A[M,K] * B[N,K]^T   (m97-verified structure)
//  - 128x128 tile, BK=64, 256 threads (4 waves, 2x2), 4x4 16x16x32 frags/wave
//  - global_load_lds width=16 staging, single LDS buffer, 2 barriers/K-step
// ---------------------------------------------------------------------------
#define TILE_M 128
#define TILE_N 128
#define TILE_K 64

#define GLOAD_LDS16(g, l) __builtin_amdgcn_global_load_lds(                  \
        (const __attribute__((address_space(1))) void*)(g),                  \
        (__attribute__((address_space(3))) void*)(l), 16, 0, 0)

__global__ __launch_bounds__(256) void gemm_bt_bf16_kernel(
        const ushort* __restrict__ A,   // [M,K] bf16 bits
        const ushort* __restrict__ B,   // [N,K] bf16 bits
        float* __restrict__ C) {        // [M,N] fp32
    __shared__ alignas(16) ushort sA[TILE_M * TILE_K];  // 16 KB
    __shared__ alignas(16) ushort sB[TILE_N * TILE_K];  // 16 KB

    const int tid  = threadIdx.x;
    const int wave = tid >> 6;
    const int lane = tid & 63;
    const int brow = blockIdx.y * TILE_M;   // M-tile
    const int bcol = blockIdx.x * TILE_N;   // N-tile
    const int wr = wave >> 1;               // 0..1: wave row
    const int wc = wave & 1;                // 0..1: wave col

    // Staging geometry: wave w, instr j writes LDS bytes [w*4096 + j*1024, +1024)
    //   -> rows [w*32+j*8, +8) of a [128][64] bf16 tile; lane covers
    //   row = w*32+j*8+(lane>>3), k = (lane&7)*8 .. +8
    const int srow = wave * 32 + (lane >> 3);
    const int scol = (lane & 7) * 8;
    const ushort* gA = A + (long)(brow + srow) * K_DIM + scol;
    const ushort* gB = B + (long)(bcol + srow) * K_DIM + scol;
    ushort* lA = sA + wave * 2048;   // elements; +j*512 per instr
    ushort* lB = sB + wave * 2048;

    const int r = lane & 15;
    const int g = lane >> 4;

    f32x4 acc[4][4] = {};

    for (int t = 0; t < K_DIM / TILE_K; ++t) {
        const ushort* gAt = gA + t * TILE_K;
        const ushort* gBt = gB + t * TILE_K;
#pragma unroll
        for (int j = 0; j < 4; ++j) {
            GLOAD_LDS16(gAt + (long)j * 8 * K_DIM, lA + j * 512);
            GLOAD_LDS16(gBt + (long)j * 8 * K_DIM, lB + j * 512);
        }
        __syncthreads();   // drains vmcnt before barrier (compiler-inserted)

#pragma unroll
        for (int kk = 0; kk < 2; ++kk) {
            short8 af[4], bfr[4];
#pragma unroll
            for (int m = 0; m < 4; ++m)
                af[m] = *(const short8*)&sA[(wr * 64 + m * 16 + r) * TILE_K + kk * 32 + g * 8];
#pragma unroll
            for (int n = 0; n < 4; ++n)
                bfr[n] = *(const short8*)&sB[(wc * 64 + n * 16 + r) * TILE_K + kk * 32 + g * 8];
#pragma unroll
            for (int m = 0; m < 4; ++m)
#pragma unroll
                for (int n = 0; n < 4; ++n)
                    acc[m][n] = __builtin_amdgcn_mfma_f32_16x16x32_bf16(
                        af[m], bfr[n], acc[m][n], 0, 0, 0);
        }
        __syncthreads();
    }

    // Epilogue: C/D layout col=lane&15, row=(lane>>4)*4+j  [m89-verified]
#pragma unroll
    for (int m = 0; m < 4; ++m) {
        const int row0 = brow + wr * 64 + m * 16 + g * 4;
#pragma unroll
        for (int n = 0; n < 4; ++n) {
            const int col = bcol + wc * 64 + n * 16 + r;
#pragma unroll
            for (int j = 0; j < 4; ++j)
                C[(long)(row0 + j) * N_DIM + col] = acc[m][n][j];
        }
    }
}

// ---------------------------------------------------------------------------
extern "C" void kernel_launch(void* const* d_in, const int* in_sizes, int n_in,
                              void* d_out, int out_size, void* d_ws, size_t ws_size,
                              hipStream_t stream) {
    const float* x      = (const float*)d_in[0];   // [4096, 4096] fp32
    const int*   qw     = (const int*)d_in[1];     // [11008, 4096] int32 codes
    const float* scales = (const float*)d_in[2];   // [11008, 32] fp32
    float* out = (float*)d_out;                    // [4096, 11008] fp32

    // ws layout: Wb bf16 [11008,4096] = 90,177,536 B ; Xb bf16 [4096,4096] = 33,554,432 B
    ushort* wb = (ushort*)d_ws;
    ushort* xb = (ushort*)((char*)d_ws + (size_t)N_DIM * K_DIM * 2);

    dequant_w_kernel<<<(N_DIM * K_DIM / 8) / 256, 256, 0, stream>>>(qw, scales, wb);
    cvt_x_kernel<<<(M_DIM * K_DIM / 8) / 256, 256, 0, stream>>>(x, xb);

    dim3 grid(N_DIM / TILE_N, M_DIM / TILE_M);  // (86, 32)
    gemm_bt_bf16_kernel<<<grid, 256, 0, stream>>>(xb, wb, out);
}

// Round 6
// 651.367 us; speedup vs baseline: 1.3305x; 1.3305x over previous
//
#include <hip/hip_runtime.h>
#include <hip/hip_bf16.h>

// Problem constants (fixed shapes from reference)
#define M_DIM 4096
#define K_DIM 4096     // IN_F
#define N_DIM 11008    // OUT_F
#define NGROUPS 32     // K/128
#define NT 64          // K_DIM / 64 K-tiles

typedef __attribute__((ext_vector_type(8))) short  short8;
typedef __attribute__((ext_vector_type(8))) unsigned short ushort8;
typedef __attribute__((ext_vector_type(4))) float  f32x4;

__device__ __forceinline__ unsigned short f2bf(float f) {
    union { float f; unsigned u; } v{f};
    unsigned r = v.u + 0x7FFFu + ((v.u >> 16) & 1u);
    return (unsigned short)(r >> 16);
}

// ---------------------------------------------------------------------------
// Pass 1a: dequantize qweight [O,K] int32 codes -> bf16 W (unchanged from v1)
// ---------------------------------------------------------------------------
__global__ __launch_bounds__(256) void dequant_w_kernel(
        const int* __restrict__ q, const float* __restrict__ scales,
        ushort* __restrict__ wb) {
    const int c = blockIdx.x * 256 + threadIdx.x;
    const int row = c >> 9;
    const int k8  = c & 511;
    const float s = scales[row * NGROUPS + (k8 >> 4)];
    const int4* qp = (const int4*)q + (long)c * 2;
    int4 a = qp[0], b = qp[1];
    ushort8 o;
    o[0] = f2bf((a.x - 8) * s); o[1] = f2bf((a.y - 8) * s);
    o[2] = f2bf((a.z - 8) * s); o[3] = f2bf((a.w - 8) * s);
    o[4] = f2bf((b.x - 8) * s); o[5] = f2bf((b.y - 8) * s);
    o[6] = f2bf((b.z - 8) * s); o[7] = f2bf((b.w - 8) * s);
    ((ushort8*)wb)[c] = o;
}

// ---------------------------------------------------------------------------
// Pass 1b: x fp32 -> bf16 (unchanged)
// ---------------------------------------------------------------------------
__global__ __launch_bounds__(256) void cvt_x_kernel(
        const float* __restrict__ x, ushort* __restrict__ xb) {
    const int c = blockIdx.x * 256 + threadIdx.x;
    const float4* xp = (const float4*)x + (long)c * 2;
    float4 a = xp[0], b = xp[1];
    ushort8 o;
    o[0] = f2bf(a.x); o[1] = f2bf(a.y); o[2] = f2bf(a.z); o[3] = f2bf(a.w);
    o[4] = f2bf(b.x); o[5] = f2bf(b.y); o[6] = f2bf(b.z); o[7] = f2bf(b.w);
    ((ushort8*)xb)[c] = o;
}

// ---------------------------------------------------------------------------
// Pass 2: 256x256x64 8-phase bf16 GEMM, C = A[M,K] * B[N,K]^T
//  8 waves (2Mx4N), per-wave 128x64 out = 8x4 frags of 16x16x32.
//  LDS 128 KB: [2 buf][A half0|A half1|B half0|B half1], half = 128x64 bf16.
//  Swizzle (both-sides involution, 16B chunks): chunk' = chunk ^ (row & 7).
//   - write: global_load_lds linear dest + pre-swizzled global source col
//   - read:  ds_read_b128 at chunk (kk*4+q) ^ (s&7)  -> 8 accesses/bank (min)
//  Schedule per group g (tile g from buf g&1): stage slots proven safe:
//   P1 rd A.kk0+B.all | stage (g+1).A1->otherbuf   (other buf: never read now)
//   P2 rd none        | stage (g+2).B0->curbuf     (B last read P1)
//   P3 rd A.kk1       | stage (g+2).B1->curbuf     (B dead since P1)
//   P4 rd none        | stage (g+2).A0->curbuf     (A last read P3), vmcnt(6)
//  vmcnt(6) = 3 half-tiles in flight; vmcnt(0) in last 2 groups (tail drain).
// ---------------------------------------------------------------------------
#define GLOAD_LDS16(g, l) __builtin_amdgcn_global_load_lds(                  \
        (const __attribute__((address_space(1))) void*)(g),                  \
        (__attribute__((address_space(3))) void*)(l), 16, 0, 0)

// stage one half-tile (128 rows x 64 cols bf16 = 16 KB) = 2 issues x 512thr x 16B
// gbase: per-thread swizzled global src for half (element ptr, row tid>>3, chunk pre-xored)
// ldsoff: byte offset of half-tile region within lds[]
#define STAGE(gbase, tile, ldsoff) do {                                      \
    GLOAD_LDS16((gbase) + ((tile) << 6),              lds + (ldsoff) + wdst);\
    GLOAD_LDS16((gbase) + (1 << 18) + ((tile) << 6),  lds + (ldsoff) + 8192 + wdst);\
  } while (0)

#define MFMA_BF16 __builtin_amdgcn_mfma_f32_16x16x32_bf16

__global__ __launch_bounds__(512, 2) void gemm256_8ph_kernel(
        const ushort* __restrict__ A,   // [M,K] bf16 bits
        const ushort* __restrict__ B,   // [N,K] bf16 bits
        float* __restrict__ C) {        // [M,N] fp32
    __shared__ alignas(16) char lds[131072];

    const int tid  = threadIdx.x;
    const int wid  = tid >> 6;
    const int lane = tid & 63;
    const int wr = wid >> 2;            // 0..1 (M)
    const int wc = wid & 3;             // 0..3 (N)
    const int s = lane & 15;            // frag row-in-16
    const int q = lane >> 4;            // frag col-group
    const int tm = blockIdx.y, tn = blockIdx.x;

    // ---- staging addressing (write side) ----
    const int trow = tid >> 3;                        // row-in-half 0..63 (issue i adds 64)
    const int tchk = (tid & 7) ^ (trow & 7);          // pre-swizzled 16B chunk
    const ushort* gAs = A + (((size_t)(tm * 256 + trow)) << 12) + tchk * 8;
    const ushort* gBs = B + (((size_t)(tn * 256 + trow)) << 12) + tchk * 8;
    const int wdst = wid << 10;                       // wave-uniform LDS dest piece

    // ---- read addressing (ds_read side) ----
    const int c0   = q ^ (s & 7);                     // swizzled chunk, kk=0 (kk=1: ^4)
    const int aoff = wr * 16384 + s * 128;            // + m*2048 + chunk*16
    const int boff = 32768 + (wc >> 1) * 16384 + ((wc & 1) * 64 + s) * 128;

    f32x4 acc[8][4] = {};

    // ---- prologue: t0 {B0,B1,A0,A1} -> buf0 ; t1 {B0,B1,A0} -> buf1 ----
    STAGE(gBs,             0, 32768);
    STAGE(gBs + (1 << 19), 0, 49152);
    STAGE(gAs,             0, 0);
    STAGE(gAs + (1 << 19), 0, 16384);
    STAGE(gBs,             1, 65536 + 32768);
    STAGE(gBs + (1 << 19), 1, 65536 + 49152);
    STAGE(gAs,             1, 65536);
    asm volatile("s_waitcnt vmcnt(6)" ::: "memory");
    __builtin_amdgcn_s_barrier();

    for (int g = 0; g < NT; ++g) {
        const int bb  = (g & 1) << 16;   // current buf byte base
        const int bb2 = bb ^ 65536;      // other buf
        const char* L = lds + bb;

        short8 a[8], bA[4], bB[4];
        // ---------------- P1: read A.kk0 (8) + B.all (8); stage (g+1).A1
#pragma unroll
        for (int m = 0; m < 8; ++m)
            a[m] = *(const short8*)(L + aoff + m * 2048 + c0 * 16);
#pragma unroll
        for (int n = 0; n < 4; ++n) {
            bA[n] = *(const short8*)(L + boff + n * 2048 + c0 * 16);
            bB[n] = *(const short8*)(L + boff + n * 2048 + (c0 ^ 4) * 16);
        }
        if (g + 1 < NT) STAGE(gAs + (1 << 19), g + 1, bb2 + 16384);
        __builtin_amdgcn_s_barrier();
        __builtin_amdgcn_s_setprio(1);
#pragma unroll
        for (int m = 0; m < 8; ++m) {
            acc[m][0] = MFMA_BF16(a[m], bA[0], acc[m][0], 0, 0, 0);
            acc[m][1] = MFMA_BF16(a[m], bA[1], acc[m][1], 0, 0, 0);
        }
        __builtin_amdgcn_s_setprio(0);
        __builtin_amdgcn_s_barrier();

        // ---------------- P2: stage (g+2).B0 -> current buf
        if (g + 2 < NT) STAGE(gBs, g + 2, bb + 32768);
        __builtin_amdgcn_s_barrier();
        __builtin_amdgcn_s_setprio(1);
#pragma unroll
        for (int m = 0; m < 8; ++m) {
            acc[m][2] = MFMA_BF16(a[m], bA[2], acc[m][2], 0, 0, 0);
            acc[m][3] = MFMA_BF16(a[m], bA[3], acc[m][3], 0, 0, 0);
        }
        __builtin_amdgcn_s_setprio(0);
        __builtin_amdgcn_s_barrier();

        // ---------------- P3: read A.kk1 (8); stage (g+2).B1 -> current buf
#pragma unroll
        for (int m = 0; m < 8; ++m)
            a[m] = *(const short8*)(L + aoff + m * 2048 + (c0 ^ 4) * 16);
        if (g + 2 < NT) STAGE(gBs + (1 << 19), g + 2, bb + 49152);
        __builtin_amdgcn_s_barrier();
        __builtin_amdgcn_s_setprio(1);
#pragma unroll
        for (int m = 0; m < 8; ++m) {
            acc[m][0] = MFMA_BF16(a[m], bB[0], acc[m][0], 0, 0, 0);
            acc[m][1] = MFMA_BF16(a[m], bB[1], acc[m][1], 0, 0, 0);
        }
        __builtin_amdgcn_s_setprio(0);
        __builtin_amdgcn_s_barrier();

        // ---------------- P4: stage (g+2).A0 -> current buf; counted vmcnt
        if (g + 2 < NT) STAGE(gAs, g + 2, bb);
        if (g < NT - 2) asm volatile("s_waitcnt vmcnt(6)" ::: "memory");
        else            asm volatile("s_waitcnt vmcnt(0)" ::: "memory");
        __builtin_amdgcn_s_barrier();
        __builtin_amdgcn_s_setprio(1);
#pragma unroll
        for (int m = 0; m < 8; ++m) {
            acc[m][2] = MFMA_BF16(a[m], bB[2], acc[m][2], 0, 0, 0);
            acc[m][3] = MFMA_BF16(a[m], bB[3], acc[m][3], 0, 0, 0);
        }
        __builtin_amdgcn_s_setprio(0);
        __builtin_amdgcn_s_barrier();
    }

    // ---- epilogue: C/D layout col=s, row=q*4+j (m89-verified) ----
    const int row0 = tm * 256 + wr * 128 + q * 4;
    const int col0 = tn * 256 + wc * 64 + s;
#pragma unroll
    for (int m = 0; m < 8; ++m)
#pragma unroll
        for (int n = 0; n < 4; ++n)
#pragma unroll
            for (int j = 0; j < 4; ++j)
                C[(size_t)(row0 + m * 16 + j) * N_DIM + col0 + n * 16] = acc[m][n][j];
}

// ---------------------------------------------------------------------------
extern "C" void kernel_launch(void* const* d_in, const int* in_sizes, int n_in,
                              void* d_out, int out_size, void* d_ws, size_t ws_size,
                              hipStream_t stream) {
    const float* x      = (const float*)d_in[0];   // [4096, 4096] fp32
    const int*   qw     = (const int*)d_in[1];     // [11008, 4096] int32 codes
    const float* scales = (const float*)d_in[2];   // [11008, 32] fp32
    float* out = (float*)d_out;                    // [4096, 11008] fp32

    ushort* wb = (ushort*)d_ws;
    ushort* xb = (ushort*)((char*)d_ws + (size_t)N_DIM * K_DIM * 2);

    dequant_w_kernel<<<(N_DIM * K_DIM / 8) / 256, 256, 0, stream>>>(qw, scales, wb);
    cvt_x_kernel<<<(M_DIM * K_DIM / 8) / 256, 256, 0, stream>>>(x, xb);

    dim3 grid(N_DIM / 256, M_DIM / 256);  // (43, 16)
    gemm256_8ph_kernel<<<grid, 512, 0, stream>>>(xb, wb, out);
}